// Round 1
// baseline (210.636 us; speedup 1.0000x reference)
//
#include <hip/hip_runtime.h>

#define BB 16
#define SS 2048
#define NTOK (BB*SS)
#define FF 512
#define EPSF 1e-5f

#if __has_builtin(__builtin_amdgcn_exp2f)
#define EXP2F(x) __builtin_amdgcn_exp2f(x)
#else
#define EXP2F(x) exp2f(x)
#endif

typedef float v2f __attribute__((ext_vector_type(2)));

// ---------------- ws float layout ----------------
// sm   : [L][64]        fused small mats (exp2-prescaled)  @ 0        (128)
// w1t  : [L][512][12]   {w1col[4], w2row[4], b1, pad3}     @ 128      (12288)
// X0   : [NTOK][4]                                         @ 12416    (131072)
// X1   : [NTOK][4]                                         @ 143488   (131072)
// feat0: [NTOK][12]     {P[4], VT[4], R, pad3}             @ 274560   (393216)
// feat1: [NTOK][12]                                        @ 667776   (393216)
// total 1,060,992 floats ~= 4.2 MB

__device__ __forceinline__ float wred64(float v) {
#pragma unroll
  for (int m = 32; m > 0; m >>= 1) v += __shfl_xor(v, m, 64);
  return v;
}

// sm layout (per layer, stride 64):
// 0:M4[16] (bw2*Wq^T Wk)   16:Bk[16] (-.5 bw2 Wk^T Wk)   32:WVO[16] (Wv*Wo)
// 48:ak[4]  52:bvo[4]  56:ck      where bw2 = bw^2 * log2(e)

// blocks 0..127: build X0 from KEY/VALUE. blocks 128..129: weight prep for layer bid-128.
__global__ __launch_bounds__(256) void prep_kernel(
    const float* __restrict__ KEY, const float* __restrict__ VALUE,
    const float* __restrict__ Wq, const float* __restrict__ bq,
    const float* __restrict__ Wk, const float* __restrict__ bk,
    const float* __restrict__ Wv, const float* __restrict__ bv,
    const float* __restrict__ Wo, const float* __restrict__ bw,
    const float* __restrict__ W1, const float* __restrict__ b1,
    const float* __restrict__ W2,
    float* __restrict__ sm, float* __restrict__ w1t, float* __restrict__ X0)
{
  const int bid = blockIdx.x;
  if (bid < 128) {
    const int gq = bid*256 + threadIdx.x;
    *(float4*)(X0 + (size_t)gq*4) =
        make_float4(KEY[gq*3 + 0], KEY[gq*3 + 1], KEY[gq*3 + 2], VALUE[gq]);
    return;
  }
  const int i = bid - 128;        // layer
  if (threadIdx.x >= 64) return;
  const int lane = threadIdx.x;   // 0..63
  float m4[4][4] = {{0}}, gkk[4][4] = {{0}}, wvo[4][4] = {{0}};
  float akk[4] = {0}, bvo[4] = {0};
  float ck1 = 0.f, ck2 = 0.f;

  for (int h = lane; h < 256; h += 64) {
    float vq[4], vk[4], vv[4], wo4[4];
#pragma unroll
    for (int a = 0; a < 4; ++a) {
      vq[a]  = Wq[(i*4 + a)*256 + h];
      vk[a]  = Wk[(i*4 + a)*256 + h];
      vv[a]  = Wv[(i*4 + a)*256 + h];
      wo4[a] = Wo[(i*256 + h)*4 + a];
    }
    const float bqh = bq[i*256 + h], bkh = bk[i*256 + h], bvh = bv[i*256 + h];
#pragma unroll
    for (int a = 0; a < 4; ++a) {
#pragma unroll
      for (int c = 0; c < 4; ++c) {
        m4[a][c]  = fmaf(vq[a], vk[c], m4[a][c]);
        gkk[a][c] = fmaf(vk[a], vk[c], gkk[a][c]);
        wvo[a][c] = fmaf(vv[a], wo4[c], wvo[a][c]);
      }
      akk[a] = fmaf(vk[a], bqh - bkh, akk[a]);
      bvo[a] = fmaf(bvh, wo4[a], bvo[a]);
    }
    ck1 = fmaf(bqh, bkh, ck1);
    ck2 = fmaf(bkh, bkh, ck2);
  }
#pragma unroll
  for (int a = 0; a < 4; ++a) {
#pragma unroll
    for (int c = 0; c < 4; ++c) {
      m4[a][c]  = wred64(m4[a][c]);
      gkk[a][c] = wred64(gkk[a][c]);
      wvo[a][c] = wred64(wvo[a][c]);
    }
    akk[a] = wred64(akk[a]);
    bvo[a] = wred64(bvo[a]);
  }
  ck1 = wred64(ck1); ck2 = wred64(ck2);

  if (lane == 0) {
    const float bwv = bw[i];
    const float bw2 = bwv * bwv * 1.44269504088896f;   // exp2 prescale
    float* s = sm + i*64;
#pragma unroll
    for (int a = 0; a < 4; ++a) {
#pragma unroll
      for (int c = 0; c < 4; ++c) {
        s[a*4+c]      = bw2 * m4[a][c];
        s[16 + a*4+c] = -0.5f * bw2 * gkk[a][c];
        s[32 + a*4+c] = wvo[a][c];
      }
      s[48+a] = bw2 * akk[a];
      s[52+a] = bvo[a];
    }
    s[56] = bw2 * (ck1 - 0.5f * ck2);
  }
  // FFN weight repack: w1t[f] = {W1[:,f], W2[f,:], b1[f], pad}
  for (int f = lane; f < FF; f += 64) {
    float* rec = w1t + (i*FF + f)*12;
#pragma unroll
    for (int c = 0; c < 4; ++c) rec[c]   = W1[(i*4 + c)*FF + f];
#pragma unroll
    for (int c = 0; c < 4; ++c) rec[4+c] = W2[(i*FF + f)*4 + c];
    rec[8] = b1[i*FF + f];
    rec[9] = 0.f; rec[10] = 0.f; rec[11] = 0.f;
  }
}

// feat record: {P[4], VT[4], R}; query-side constant dropped (cancels in softmax)
__device__ __forceinline__ void compute_feat(const float x[4], const float* __restrict__ s,
                                             float* __restrict__ featrec)
{
  float P[4], VT[4], tk[4];
#pragma unroll
  for (int a = 0; a < 4; ++a) {
    P[a]  = fmaf(s[a*4+3], x[3], fmaf(s[a*4+2], x[2], fmaf(s[a*4+1], x[1], s[a*4+0]*x[0])));
    tk[a] = fmaf(s[16+a*4+3], x[3], fmaf(s[16+a*4+2], x[2], fmaf(s[16+a*4+1], x[1], s[16+a*4+0]*x[0])));
    VT[a] = s[52+a] + fmaf(s[32+3*4+a], x[3], fmaf(s[32+2*4+a], x[2], fmaf(s[32+1*4+a], x[1], s[32+0*4+a]*x[0])));
  }
  float R = s[56];
#pragma unroll
  for (int a = 0; a < 4; ++a) R = fmaf(tk[a] + s[48+a], x[a], R);
  float4* fp = (float4*)featrec;
  fp[0] = make_float4(P[0], P[1], P[2], P[3]);
  fp[1] = make_float4(VT[0], VT[1], VT[2], VT[3]);
  fp[2] = make_float4(R, 0.f, 0.f, 0.f);
}

// one key-feature record per token, from X and the layer's small mats
__global__ __launch_bounds__(256) void feat_kernel(
    const float* __restrict__ X, const float* __restrict__ sm, float* __restrict__ feat)
{
  const int gq = blockIdx.x*256 + threadIdx.x;
  const float4 xv = *(const float4*)(X + (size_t)gq*4);
  float xr[4] = {xv.x, xv.y, xv.z, xv.w};
  float fr[12];
  compute_feat(xr, sm, fr);
  float4* fp = (float4*)(feat + (size_t)gq*12);
  fp[0] = ((float4*)fr)[0];
  fp[1] = ((float4*)fr)[1];
  fp[2] = ((float4*)fr)[2];
}

__device__ __forceinline__ void ln4(const float t[4], const float* __restrict__ g,
                                    const float* __restrict__ b, float r[4])
{
  const float m = 0.25f*(t[0]+t[1]+t[2]+t[3]);
  const float d0 = t[0]-m, d1 = t[1]-m, d2 = t[2]-m, d3 = t[3]-m;
  const float v = 0.25f*(d0*d0 + d1*d1 + d2*d2 + d3*d3);
  const float sc = rsqrtf(v + EPSF);
  r[0] = fmaf(d0*sc, g[0], b[0]);
  r[1] = fmaf(d1*sc, g[1], b[1]);
  r[2] = fmaf(d2*sc, g[2], b[2]);
  r[3] = fmaf(d3*sc, g[3], b[3]);
}

// Fused per-layer kernel: block = 512 thr, 64 queries x 2048 keys (all of batch b).
// Key feats read straight from L2-resident feat[] (96 KB/batch) - no LDS staging.
// Slices: (wave, half-wave) -> 16 slices x 128 keys. 2 queries/lane pk-packed.
// Then: half-reduce (shfl_xor 32), wave-reduce (LDS), softmax-normalize,
// +residual, LN1, FFN (8 fc x 64 f), LN2, write Xout + next-layer feats (or final fc).
__global__ __launch_bounds__(512, 4) void layer_kernel(
    const float* __restrict__ X, const float* __restrict__ feat,
    const float* __restrict__ w1t, const float* __restrict__ smn,
    const float* __restrict__ bo, const float* __restrict__ g1, const float* __restrict__ be1,
    const float* __restrict__ b2v, const float* __restrict__ g2, const float* __restrict__ be2,
    float* __restrict__ Xout, float* __restrict__ featout,
    const float* __restrict__ Wfc, const float* __restrict__ bfc,
    float* __restrict__ outp, int last)
{
  const int bid = blockIdx.x;
  const int b = bid >> 5, qg = bid & 31;
  const int qbase = (b << 11) + (qg << 6);     // 64 queries
  const int tid = threadIdx.x;
  const int lane = tid & 63, wave = tid >> 6;
  const int j = lane & 31, half = lane >> 5;

  __shared__ float red[8][32][12];   // per-wave qpair partials {q0V[4], q1V[4], d0, d1, pad2}
  __shared__ float ress[64][4];
  __shared__ float redf[8][64][4];

  // 2 queries per lane, component-packed for v_pk_fma_f32
  v2f xq0, xq1, xq2v, xq3;
  {
    const float4 xa = *(const float4*)(X + (size_t)(qbase + 2*j    )*4);
    const float4 xb = *(const float4*)(X + (size_t)(qbase + 2*j + 1)*4);
    xq0  = v2f{xa.x, xb.x}; xq1 = v2f{xa.y, xb.y};
    xq2v = v2f{xa.z, xb.z}; xq3 = v2f{xa.w, xb.w};
  }
  v2f a0xy = v2f{0.f,0.f}, a0zw = v2f{0.f,0.f};
  v2f a1xy = v2f{0.f,0.f}, a1zw = v2f{0.f,0.f};
  v2f ad   = v2f{0.f,0.f};

  // this (wave, half)'s 128-key slice; broadcast loads (uniform per half-wave)
  const float* kp = feat + (size_t)((b << 11) + (wave*2 + half)*128) * 12;
#pragma unroll 4
  for (int k = 0; k < 128; ++k) {
    const float4 P  = *(const float4*)(kp + k*12);
    const float4 VT = *(const float4*)(kp + k*12 + 4);
    const float  R  = kp[k*12 + 8];
    v2f l = __builtin_elementwise_fma(xq0, v2f{P.x, P.x}, v2f{R, R});
    l = __builtin_elementwise_fma(xq1,  v2f{P.y, P.y}, l);
    l = __builtin_elementwise_fma(xq2v, v2f{P.z, P.z}, l);
    l = __builtin_elementwise_fma(xq3,  v2f{P.w, P.w}, l);
    const float e0 = EXP2F(l.x);
    const float e1 = EXP2F(l.y);
    const v2f Vxy = v2f{VT.x, VT.y}, Vzw = v2f{VT.z, VT.w};
    const v2f e0v = v2f{e0, e0}, e1v = v2f{e1, e1};
    a0xy = __builtin_elementwise_fma(e0v, Vxy, a0xy);
    a0zw = __builtin_elementwise_fma(e0v, Vzw, a0zw);
    a1xy = __builtin_elementwise_fma(e1v, Vxy, a1xy);
    a1zw = __builtin_elementwise_fma(e1v, Vzw, a1zw);
    ad += v2f{e0, e1};
  }

  // reduce the two half-waves (they hold different keys for the same qpairs)
  float v10[10] = {a0xy.x, a0xy.y, a0zw.x, a0zw.y,
                   a1xy.x, a1xy.y, a1zw.x, a1zw.y, ad.x, ad.y};
#pragma unroll
  for (int c = 0; c < 10; ++c) v10[c] += __shfl_xor(v10[c], 32, 64);
  if (half == 0) {
    float* rr = &red[wave][j][0];
    *(float4*)rr       = make_float4(v10[0], v10[1], v10[2], v10[3]);
    *(float4*)(rr + 4) = make_float4(v10[4], v10[5], v10[6], v10[7]);
    rr[8] = v10[8]; rr[9] = v10[9];
  }
  __syncthreads();

  // wave-reduce + softmax normalize + residual + LN1 (token t handled by thread t)
  if (tid < 64) {
    const int jj = tid >> 1, p = tid & 1;
    float sv0 = 0.f, sv1 = 0.f, sv2 = 0.f, sv3 = 0.f, sd = 0.f;
#pragma unroll
    for (int w = 0; w < 8; ++w) {
      const float4 vv = *(const float4*)&red[w][jj][p*4];
      sv0 += vv.x; sv1 += vv.y; sv2 += vv.z; sv3 += vv.w;
      sd  += red[w][jj][8 + p];
    }
    const float inv = 1.0f / sd;
    const float4 xv = *(const float4*)(X + (size_t)(qbase + tid)*4);
    float t4[4];
    t4[0] = xv.x + fmaf(sv0, inv, bo[0]);
    t4[1] = xv.y + fmaf(sv1, inv, bo[1]);
    t4[2] = xv.z + fmaf(sv2, inv, bo[2]);
    t4[3] = xv.w + fmaf(sv3, inv, bo[3]);
    float r[4];
    ln4(t4, g1, be1, r);
    *(float4*)&ress[tid][0] = make_float4(r[0], r[1], r[2], r[3]);
  }
  __syncthreads();

  // FFN: fc = wave (8 chunks of 64 f), tok = lane
  const int tok = lane, fc = wave;
  const float4 rv = *(const float4*)&ress[tok][0];
  float fa0 = 0.f, fa1 = 0.f, fa2 = 0.f, fa3 = 0.f;
  const float* wt = w1t + (size_t)fc*64*12;
#pragma unroll 4
  for (int f = 0; f < 64; ++f) {
    const float* rec = wt + f*12;
    const float4 w1r = *(const float4*)rec;
    const float4 w2r = *(const float4*)(rec + 4);
    const float b1f = rec[8];
    float h = fmaf(rv.w, w1r.w, fmaf(rv.z, w1r.z, fmaf(rv.y, w1r.y, fmaf(rv.x, w1r.x, b1f))));
    h = fmaxf(h, 0.f);
    fa0 = fmaf(h, w2r.x, fa0);
    fa1 = fmaf(h, w2r.y, fa1);
    fa2 = fmaf(h, w2r.z, fa2);
    fa3 = fmaf(h, w2r.w, fa3);
  }
  *(float4*)&redf[fc][tok][0] = make_float4(fa0, fa1, fa2, fa3);
  __syncthreads();

  // FFN reduce + residual + LN2 + output (X + next-layer feats, or final fc)
  if (tid < 64) {
    float t2[4];
#pragma unroll
    for (int c = 0; c < 4; ++c) {
      float s = b2v[c];
#pragma unroll
      for (int k = 0; k < 8; ++k) s += redf[k][tid][c];
      t2[c] = ress[tid][c] + s;
    }
    float y[4];
    ln4(t2, g2, be2, y);
    const int gq = qbase + tid;
    if (last) {
      outp[gq] = fmaf(y[3], Wfc[3], fmaf(y[2], Wfc[2], fmaf(y[1], Wfc[1], fmaf(y[0], Wfc[0], bfc[0]))));
    } else {
      *(float4*)(Xout + (size_t)gq*4) = make_float4(y[0], y[1], y[2], y[3]);
      float fr[12];
      compute_feat(y, smn, fr);
      float4* fp = (float4*)(featout + (size_t)gq*12);
      fp[0] = ((float4*)fr)[0];
      fp[1] = ((float4*)fr)[1];
      fp[2] = ((float4*)fr)[2];
    }
  }
}

extern "C" void kernel_launch(void* const* d_in, const int* in_sizes, int n_in,
                              void* d_out, int out_size, void* d_ws, size_t ws_size,
                              hipStream_t stream)
{
  const float* KEY   = (const float*)d_in[0];
  const float* VALUE = (const float*)d_in[1];
  const float* Wq  = (const float*)d_in[2];
  const float* bq  = (const float*)d_in[3];
  const float* Wk  = (const float*)d_in[4];
  const float* bk  = (const float*)d_in[5];
  const float* Wv  = (const float*)d_in[6];
  const float* bv  = (const float*)d_in[7];
  const float* Wo  = (const float*)d_in[8];
  const float* bo  = (const float*)d_in[9];
  const float* bw  = (const float*)d_in[10];
  const float* g1  = (const float*)d_in[11];
  const float* be1 = (const float*)d_in[12];
  const float* W1  = (const float*)d_in[13];
  const float* b1  = (const float*)d_in[14];
  const float* W2  = (const float*)d_in[15];
  const float* b2  = (const float*)d_in[16];
  const float* g2  = (const float*)d_in[17];
  const float* be2 = (const float*)d_in[18];
  const float* Wfc = (const float*)d_in[19];
  const float* bfc = (const float*)d_in[20];
  float* out = (float*)d_out;

  float* w    = (float*)d_ws;
  float* sm   = w;              // 128
  float* w1t  = w + 128;        // 12288
  float* X0   = w + 12416;      // 131072
  float* X1   = w + 143488;     // 131072
  float* f0   = w + 274560;     // 393216
  float* f1   = w + 667776;     // 393216

  prep_kernel<<<130, 256, 0, stream>>>(KEY, VALUE, Wq, bq, Wk, bk, Wv, bv, Wo, bw,
                                       W1, b1, W2, sm, w1t, X0);
  feat_kernel<<<128, 256, 0, stream>>>(X0, sm, f0);

  // layer 0: consumes feat0/X0, produces X1 + feat1 (using layer 1's small mats)
  layer_kernel<<<512, 512, 0, stream>>>(X0, f0, w1t, sm + 64,
      bo, g1, be1, b2, g2, be2,
      X1, f1, Wfc, bfc, out, 0);

  // layer 1: consumes feat1/X1, produces final output
  layer_kernel<<<512, 512, 0, stream>>>(X1, f1, w1t + FF*12, sm,
      bo + 4, g1 + 4, be1 + 4, b2 + 4, g2 + 4, be2 + 4,
      X0, f0, Wfc, bfc, out, 1);
}

// Round 2
// 171.339 us; speedup vs baseline: 1.2294x; 1.2294x over previous
//
#include <hip/hip_runtime.h>

#define BB 16
#define SS 2048
#define NTOK (BB*SS)
#define FF 512
#define EPSF 1e-5f

#if __has_builtin(__builtin_amdgcn_exp2f)
#define EXP2F(x) __builtin_amdgcn_exp2f(x)
#else
#define EXP2F(x) exp2f(x)
#endif

typedef float v2f __attribute__((ext_vector_type(2)));

// ---------------- ws float layout ----------------
// sm   : [L][64]        fused small mats (exp2-prescaled)  @ 0        (128)
// w1t  : [L][512][12]   {w1col[4], w2row[4], b1, pad3}     @ 128      (12288)
// X0   : [NTOK][4]                                         @ 12416    (131072)
// X1   : [NTOK][4]                                         @ 143488   (131072)
// f0P  : [NTOK][4]                                         @ 274560   (131072)
// f0V  : [NTOK][4]                                         @ 405632   (131072)
// f0R  : [NTOK]                                            @ 536704   (32768)
// f1P  : [NTOK][4]                                         @ 569472   (131072)
// f1V  : [NTOK][4]                                         @ 700544   (131072)
// f1R  : [NTOK]                                            @ 831616   (32768)
// total 864,384 floats ~= 3.5 MB

__device__ __forceinline__ float wred64(float v) {
#pragma unroll
  for (int m = 32; m > 0; m >>= 1) v += __shfl_xor(v, m, 64);
  return v;
}

// sm layout (per layer, stride 64):
// 0:M4[16] (bw2*Wq^T Wk)   16:Bk[16] (-.5 bw2 Wk^T Wk)   32:WVO[16] (Wv*Wo)
// 48:ak[4]  52:bvo[4]  56:ck      where bw2 = bw^2 * log2(e)

// blocks 0..127: build X0 from KEY/VALUE. blocks 128..129: weight prep for layer bid-128.
__global__ __launch_bounds__(256) void prep_kernel(
    const float* __restrict__ KEY, const float* __restrict__ VALUE,
    const float* __restrict__ Wq, const float* __restrict__ bq,
    const float* __restrict__ Wk, const float* __restrict__ bk,
    const float* __restrict__ Wv, const float* __restrict__ bv,
    const float* __restrict__ Wo, const float* __restrict__ bw,
    const float* __restrict__ W1, const float* __restrict__ b1,
    const float* __restrict__ W2,
    float* __restrict__ sm, float* __restrict__ w1t, float* __restrict__ X0)
{
  const int bid = blockIdx.x;
  if (bid < 128) {
    const int gq = bid*256 + threadIdx.x;
    *(float4*)(X0 + (size_t)gq*4) =
        make_float4(KEY[gq*3 + 0], KEY[gq*3 + 1], KEY[gq*3 + 2], VALUE[gq]);
    return;
  }
  const int i = bid - 128;        // layer
  if (threadIdx.x >= 64) return;
  const int lane = threadIdx.x;   // 0..63
  float m4[4][4] = {{0}}, gkk[4][4] = {{0}}, wvo[4][4] = {{0}};
  float akk[4] = {0}, bvo[4] = {0};
  float ck1 = 0.f, ck2 = 0.f;

  for (int h = lane; h < 256; h += 64) {
    float vq[4], vk[4], vv[4], wo4[4];
#pragma unroll
    for (int a = 0; a < 4; ++a) {
      vq[a]  = Wq[(i*4 + a)*256 + h];
      vk[a]  = Wk[(i*4 + a)*256 + h];
      vv[a]  = Wv[(i*4 + a)*256 + h];
      wo4[a] = Wo[(i*256 + h)*4 + a];
    }
    const float bqh = bq[i*256 + h], bkh = bk[i*256 + h], bvh = bv[i*256 + h];
#pragma unroll
    for (int a = 0; a < 4; ++a) {
#pragma unroll
      for (int c = 0; c < 4; ++c) {
        m4[a][c]  = fmaf(vq[a], vk[c], m4[a][c]);
        gkk[a][c] = fmaf(vk[a], vk[c], gkk[a][c]);
        wvo[a][c] = fmaf(vv[a], wo4[c], wvo[a][c]);
      }
      akk[a] = fmaf(vk[a], bqh - bkh, akk[a]);
      bvo[a] = fmaf(bvh, wo4[a], bvo[a]);
    }
    ck1 = fmaf(bqh, bkh, ck1);
    ck2 = fmaf(bkh, bkh, ck2);
  }
#pragma unroll
  for (int a = 0; a < 4; ++a) {
#pragma unroll
    for (int c = 0; c < 4; ++c) {
      m4[a][c]  = wred64(m4[a][c]);
      gkk[a][c] = wred64(gkk[a][c]);
      wvo[a][c] = wred64(wvo[a][c]);
    }
    akk[a] = wred64(akk[a]);
    bvo[a] = wred64(bvo[a]);
  }
  ck1 = wred64(ck1); ck2 = wred64(ck2);

  if (lane == 0) {
    const float bwv = bw[i];
    const float bw2 = bwv * bwv * 1.44269504088896f;   // exp2 prescale
    float* s = sm + i*64;
#pragma unroll
    for (int a = 0; a < 4; ++a) {
#pragma unroll
      for (int c = 0; c < 4; ++c) {
        s[a*4+c]      = bw2 * m4[a][c];
        s[16 + a*4+c] = -0.5f * bw2 * gkk[a][c];
        s[32 + a*4+c] = wvo[a][c];
      }
      s[48+a] = bw2 * akk[a];
      s[52+a] = bvo[a];
    }
    s[56] = bw2 * (ck1 - 0.5f * ck2);
  }
  // FFN weight repack: w1t[f] = {W1[:,f], W2[f,:], b1[f], pad}
  for (int f = lane; f < FF; f += 64) {
    float* rec = w1t + (i*FF + f)*12;
#pragma unroll
    for (int c = 0; c < 4; ++c) rec[c]   = W1[(i*4 + c)*FF + f];
#pragma unroll
    for (int c = 0; c < 4; ++c) rec[4+c] = W2[(i*FF + f)*4 + c];
    rec[8] = b1[i*FF + f];
    rec[9] = 0.f; rec[10] = 0.f; rec[11] = 0.f;
  }
}

// feat record: {P[4], VT[4], R}; query-side constant dropped (cancels in softmax)
__device__ __forceinline__ void compute_feat(const float x[4], const float* __restrict__ s,
                                             float* __restrict__ featrec)
{
  float P[4], VT[4], tk[4];
#pragma unroll
  for (int a = 0; a < 4; ++a) {
    P[a]  = fmaf(s[a*4+3], x[3], fmaf(s[a*4+2], x[2], fmaf(s[a*4+1], x[1], s[a*4+0]*x[0])));
    tk[a] = fmaf(s[16+a*4+3], x[3], fmaf(s[16+a*4+2], x[2], fmaf(s[16+a*4+1], x[1], s[16+a*4+0]*x[0])));
    VT[a] = s[52+a] + fmaf(s[32+3*4+a], x[3], fmaf(s[32+2*4+a], x[2], fmaf(s[32+1*4+a], x[1], s[32+0*4+a]*x[0])));
  }
  float R = s[56];
#pragma unroll
  for (int a = 0; a < 4; ++a) R = fmaf(tk[a] + s[48+a], x[a], R);
  float4* fp = (float4*)featrec;
  fp[0] = make_float4(P[0], P[1], P[2], P[3]);
  fp[1] = make_float4(VT[0], VT[1], VT[2], VT[3]);
  fp[2] = make_float4(R, 0.f, 0.f, 0.f);
}

// one key-feature record per token (SoA planes), from X and the layer's small mats
__global__ __launch_bounds__(256) void feat_kernel(
    const float* __restrict__ X, const float* __restrict__ sm,
    float* __restrict__ fP, float* __restrict__ fV, float* __restrict__ fR)
{
  const int gq = blockIdx.x*256 + threadIdx.x;
  const float4 xv = *(const float4*)(X + (size_t)gq*4);
  float xr[4] = {xv.x, xv.y, xv.z, xv.w};
  float fr[12];
  compute_feat(xr, sm, fr);
  *(float4*)(fP + (size_t)gq*4) = ((float4*)fr)[0];
  *(float4*)(fV + (size_t)gq*4) = ((float4*)fr)[1];
  fR[gq] = fr[8];
}

__device__ __forceinline__ void ln4(const float t[4], const float* __restrict__ g,
                                    const float* __restrict__ b, float r[4])
{
  const float m = 0.25f*(t[0]+t[1]+t[2]+t[3]);
  const float d0 = t[0]-m, d1 = t[1]-m, d2 = t[2]-m, d3 = t[3]-m;
  const float v = 0.25f*(d0*d0 + d1*d1 + d2*d2 + d3*d3);
  const float sc = rsqrtf(v + EPSF);
  r[0] = fmaf(d0*sc, g[0], b[0]);
  r[1] = fmaf(d1*sc, g[1], b[1]);
  r[2] = fmaf(d2*sc, g[2], b[2]);
  r[3] = fmaf(d3*sc, g[3], b[3]);
}

// Fused per-layer kernel: block = 512 thr (8 waves), 64 queries x all 2048 keys.
// Keys: feat planes -> regs (issued early) -> LDS (written late) -> ds_read broadcast.
// 4 double-buffered chunks of 512 keys; (wave,half) slice = 32 keys/chunk.
// 2 queries/lane pk-packed; half-reduce (shfl_xor 32), wave-reduce (LDS),
// softmax-normalize, +residual, LN1, FFN (8 fc x 64 f), LN2, outputs.
__global__ __launch_bounds__(512, 4) void layer_kernel(
    const float* __restrict__ X,
    const float* __restrict__ fP, const float* __restrict__ fV, const float* __restrict__ fR,
    const float* __restrict__ w1t, const float* __restrict__ smn,
    const float* __restrict__ bo, const float* __restrict__ g1, const float* __restrict__ be1,
    const float* __restrict__ b2v, const float* __restrict__ g2, const float* __restrict__ be2,
    float* __restrict__ Xout,
    float* __restrict__ foP, float* __restrict__ foV, float* __restrict__ foR,
    const float* __restrict__ Wfc, const float* __restrict__ bfc,
    float* __restrict__ outp, int last)
{
  const int bid = blockIdx.x;
  const int b = bid >> 5, qg = bid & 31;
  const int qbase = (b << 11) + (qg << 6);     // 64 queries
  const int kbase0 = (b << 11);
  const int tid = threadIdx.x;
  const int lane = tid & 63, wave = tid >> 6;
  const int j = lane & 31, half = lane >> 5;
  const int slice = wave*2 + half;             // 0..15, 32 keys per chunk

  // single 48KB arena: kbuf[2][512][12] aliased with reduction scratch
  __shared__ float smem[2*512*12];
  float* red  = smem;          // [8][32][12] = 3072 floats (after final barrier)
  float* ress = smem + 3072;   // [64][4]
  float* redf = smem + 3328;   // [8][64][4]

  // 2 queries per lane, component-packed for v_pk_fma_f32
  v2f xq0, xq1, xq2v, xq3;
  {
    const float4 xa = *(const float4*)(X + (size_t)(qbase + 2*j    )*4);
    const float4 xb = *(const float4*)(X + (size_t)(qbase + 2*j + 1)*4);
    xq0  = v2f{xa.x, xb.x}; xq1 = v2f{xa.y, xb.y};
    xq2v = v2f{xa.z, xb.z}; xq3 = v2f{xa.w, xb.w};
  }
  v2f a0xy = v2f{0.f,0.f}, a0zw = v2f{0.f,0.f};
  v2f a1xy = v2f{0.f,0.f}, a1zw = v2f{0.f,0.f};
  v2f ad   = v2f{0.f,0.f};

  // stage chunk 0
  float4 sP, sV; float sR;
  {
    const int kk = kbase0 + tid;
    sP = *(const float4*)(fP + (size_t)kk*4);
    sV = *(const float4*)(fV + (size_t)kk*4);
    sR = fR[kk];
  }
  {
    float* d = smem + tid*12;
    *(float4*)d = sP; *(float4*)(d+4) = sV; d[8] = sR;
  }
  __syncthreads();

#pragma unroll
  for (int c = 0; c < 4; ++c) {
    if (c < 3) {               // issue next chunk's loads early (latency hides under compute)
      const int kk = kbase0 + (c+1)*512 + tid;
      sP = *(const float4*)(fP + (size_t)kk*4);
      sV = *(const float4*)(fV + (size_t)kk*4);
      sR = fR[kk];
    }
    const float* kf = smem + (c & 1)*6144 + slice*384;   // 32 keys * 12 floats
#pragma unroll 4
    for (int k = 0; k < 32; ++k) {
      const float* rec = kf + k*12;
      const float4 P  = *(const float4*)rec;
      const float4 VT = *(const float4*)(rec + 4);
      const float  R  = rec[8];
      v2f l = __builtin_elementwise_fma(xq0, v2f{P.x, P.x}, v2f{R, R});
      l = __builtin_elementwise_fma(xq1,  v2f{P.y, P.y}, l);
      l = __builtin_elementwise_fma(xq2v, v2f{P.z, P.z}, l);
      l = __builtin_elementwise_fma(xq3,  v2f{P.w, P.w}, l);
      const float e0 = EXP2F(l.x);
      const float e1 = EXP2F(l.y);
      const v2f Vxy = v2f{VT.x, VT.y}, Vzw = v2f{VT.z, VT.w};
      const v2f e0v = v2f{e0, e0}, e1v = v2f{e1, e1};
      a0xy = __builtin_elementwise_fma(e0v, Vxy, a0xy);
      a0zw = __builtin_elementwise_fma(e0v, Vzw, a0zw);
      a1xy = __builtin_elementwise_fma(e1v, Vxy, a1xy);
      a1zw = __builtin_elementwise_fma(e1v, Vzw, a1zw);
      ad += v2f{e0, e1};
    }
    if (c < 3) {               // write-late into the other buffer (no race: readers use buf c&1)
      float* d = smem + ((c+1) & 1)*6144 + tid*12;
      *(float4*)d = sP; *(float4*)(d+4) = sV; d[8] = sR;
    }
    __syncthreads();
  }

  // reduce the two half-waves (same queries, different keys)
  float v10[10] = {a0xy.x, a0xy.y, a0zw.x, a0zw.y,
                   a1xy.x, a1xy.y, a1zw.x, a1zw.y, ad.x, ad.y};
#pragma unroll
  for (int c = 0; c < 10; ++c) v10[c] += __shfl_xor(v10[c], 32, 64);
  if (half == 0) {
    float* rr = red + (wave*32 + j)*12;
    *(float4*)rr       = make_float4(v10[0], v10[1], v10[2], v10[3]);
    *(float4*)(rr + 4) = make_float4(v10[4], v10[5], v10[6], v10[7]);
    rr[8] = v10[8]; rr[9] = v10[9];
  }
  __syncthreads();

  // wave-reduce + softmax normalize + residual + LN1 (token t handled by thread t)
  if (tid < 64) {
    const int jj = tid >> 1, p = tid & 1;
    float sv0 = 0.f, sv1 = 0.f, sv2 = 0.f, sv3 = 0.f, sd = 0.f;
#pragma unroll
    for (int w = 0; w < 8; ++w) {
      const float* rr = red + (w*32 + jj)*12;
      const float4 vv = *(const float4*)(rr + p*4);
      sv0 += vv.x; sv1 += vv.y; sv2 += vv.z; sv3 += vv.w;
      sd  += rr[8 + p];
    }
    const float inv = 1.0f / sd;
    const float4 xv = *(const float4*)(X + (size_t)(qbase + tid)*4);
    float t4[4];
    t4[0] = xv.x + fmaf(sv0, inv, bo[0]);
    t4[1] = xv.y + fmaf(sv1, inv, bo[1]);
    t4[2] = xv.z + fmaf(sv2, inv, bo[2]);
    t4[3] = xv.w + fmaf(sv3, inv, bo[3]);
    float r[4];
    ln4(t4, g1, be1, r);
    *(float4*)(ress + tid*4) = make_float4(r[0], r[1], r[2], r[3]);
  }
  __syncthreads();

  // FFN: fc = wave (8 chunks of 64 f), tok = lane
  const int tok = lane, fc = wave;
  const float4 rv = *(const float4*)(ress + tok*4);
  float fa0 = 0.f, fa1 = 0.f, fa2 = 0.f, fa3 = 0.f;
  const float* wt = w1t + (size_t)fc*64*12;
#pragma unroll 4
  for (int f = 0; f < 64; ++f) {
    const float* rec = wt + f*12;
    const float4 w1r = *(const float4*)rec;
    const float4 w2r = *(const float4*)(rec + 4);
    const float b1f = rec[8];
    float h = fmaf(rv.w, w1r.w, fmaf(rv.z, w1r.z, fmaf(rv.y, w1r.y, fmaf(rv.x, w1r.x, b1f))));
    h = fmaxf(h, 0.f);
    fa0 = fmaf(h, w2r.x, fa0);
    fa1 = fmaf(h, w2r.y, fa1);
    fa2 = fmaf(h, w2r.z, fa2);
    fa3 = fmaf(h, w2r.w, fa3);
  }
  *(float4*)(redf + (fc*64 + tok)*4) = make_float4(fa0, fa1, fa2, fa3);
  __syncthreads();

  // FFN reduce + residual + LN2 + output (X + next-layer feats, or final fc)
  if (tid < 64) {
    float t2[4];
#pragma unroll
    for (int c = 0; c < 4; ++c) {
      float s = b2v[c];
#pragma unroll
      for (int k = 0; k < 8; ++k) s += redf[(k*64 + tid)*4 + c];
      t2[c] = ress[tid*4 + c] + s;
    }
    float y[4];
    ln4(t2, g2, be2, y);
    const int gq = qbase + tid;
    if (last) {
      outp[gq] = fmaf(y[3], Wfc[3], fmaf(y[2], Wfc[2], fmaf(y[1], Wfc[1], fmaf(y[0], Wfc[0], bfc[0]))));
    } else {
      *(float4*)(Xout + (size_t)gq*4) = make_float4(y[0], y[1], y[2], y[3]);
      float fr[12];
      compute_feat(y, smn, fr);
      *(float4*)(foP + (size_t)gq*4) = ((float4*)fr)[0];
      *(float4*)(foV + (size_t)gq*4) = ((float4*)fr)[1];
      foR[gq] = fr[8];
    }
  }
}

extern "C" void kernel_launch(void* const* d_in, const int* in_sizes, int n_in,
                              void* d_out, int out_size, void* d_ws, size_t ws_size,
                              hipStream_t stream)
{
  const float* KEY   = (const float*)d_in[0];
  const float* VALUE = (const float*)d_in[1];
  const float* Wq  = (const float*)d_in[2];
  const float* bq  = (const float*)d_in[3];
  const float* Wk  = (const float*)d_in[4];
  const float* bk  = (const float*)d_in[5];
  const float* Wv  = (const float*)d_in[6];
  const float* bv  = (const float*)d_in[7];
  const float* Wo  = (const float*)d_in[8];
  const float* bo  = (const float*)d_in[9];
  const float* bw  = (const float*)d_in[10];
  const float* g1  = (const float*)d_in[11];
  const float* be1 = (const float*)d_in[12];
  const float* W1  = (const float*)d_in[13];
  const float* b1  = (const float*)d_in[14];
  const float* W2  = (const float*)d_in[15];
  const float* b2  = (const float*)d_in[16];
  const float* g2  = (const float*)d_in[17];
  const float* be2 = (const float*)d_in[18];
  const float* Wfc = (const float*)d_in[19];
  const float* bfc = (const float*)d_in[20];
  float* out = (float*)d_out;

  float* w    = (float*)d_ws;
  float* sm   = w;              // 128
  float* w1t  = w + 128;        // 12288
  float* X0   = w + 12416;      // 131072
  float* X1   = w + 143488;     // 131072
  float* f0P  = w + 274560;     // 131072
  float* f0V  = w + 405632;     // 131072
  float* f0R  = w + 536704;     // 32768
  float* f1P  = w + 569472;     // 131072
  float* f1V  = w + 700544;     // 131072
  float* f1R  = w + 831616;     // 32768

  prep_kernel<<<130, 256, 0, stream>>>(KEY, VALUE, Wq, bq, Wk, bk, Wv, bv, Wo, bw,
                                       W1, b1, W2, sm, w1t, X0);
  feat_kernel<<<128, 256, 0, stream>>>(X0, sm, f0P, f0V, f0R);

  // layer 0: consumes feat0/X0, produces X1 + feat1 (using layer 1's small mats)
  layer_kernel<<<512, 512, 0, stream>>>(X0, f0P, f0V, f0R, w1t, sm + 64,
      bo, g1, be1, b2, g2, be2,
      X1, f1P, f1V, f1R, Wfc, bfc, out, 0);

  // layer 1: consumes feat1/X1, produces final output
  layer_kernel<<<512, 512, 0, stream>>>(X1, f1P, f1V, f1R, w1t + FF*12, sm,
      bo + 4, g1 + 4, be1 + 4, b2 + 4, g2 + 4, be2 + 4,
      X0, f0P, f0V, f0R, Wfc, bfc, out, 1);
}